// Round 6
// baseline (63.969 us; speedup 1.0000x reference)
//
#include <hip/hip_runtime.h>

typedef float fvec2 __attribute__((ext_vector_type(2)));
typedef float fvec4 __attribute__((ext_vector_type(4)));

// Fully fused 3-level inverse 3D Haar DWT.
// out(B,128,128,128) from scale0(B,8,64^3), scale1(B,8,32^3), scale2(B,8,16^3).
// Subband s = 4*b0 + 2*b1 + b2 (b0 -> D, b1 -> H, b2 -> W); inverse level:
// out(2d+io,2h+jo,2w+ko) = 2^{-3/2} * sum_s c_s * (-1)^(io*b0+jo*b1+ko*b2).
//
// One thread per (level-1 voxel PAIR, i, j): w1 = 2*tw+u for u=0,1.
//   - (i,j) split across threads keeps VGPR low (R5 lesson: occupancy wins)
//   - w-pair keeps scale0 loads at 16 B/lane (R4 lesson applied narrowly)
// Per thread: 8 scalar scale2 loads, 7 fvec2 scale1 loads, 7 fvec4 scale0
// loads, 8 fvec4 stores (rows 2d0+io / 2h0+jo, w in [8tw, 8tw+8)).

__global__ __launch_bounds__(256) void idwt3_fused_kernel(
    const float* __restrict__ scale0, const float* __restrict__ scale1,
    const float* __restrict__ scale2, float* __restrict__ out, int B) {
    constexpr float SC = 0.35355339059327373f;  // 2^{-3/2}

    const int idx = blockIdx.x * 256 + threadIdx.x;
    const int tw = idx & 15;          // level-1 w-pair: w1 = 2*tw + u
    const int j = (idx >> 4) & 1;
    const int i = (idx >> 5) & 1;
    const int h1 = (idx >> 6) & 31;
    const int d1 = (idx >> 11) & 31;
    const int b = idx >> 16;
    if (b >= B) return;

    // ---- level 2: approx2 at (d1, h1, 2tw+u), u = 0,1 (k2 = u, w2 = tw) ----
    const int d2 = d1 >> 1, h2 = h1 >> 1;
    const int i2 = d1 & 1, j2 = h1 & 1;
    constexpr size_t p2 = 16 * 16 * 16;
    const float* s2 = scale2 + (size_t)b * 8 * p2 + ((size_t)d2 * 16 + h2) * 16 + tw;
    float a2[2];
    {
        float c2[8];
#pragma unroll
        for (int s = 0; s < 8; ++s) c2[s] = s2[s * p2];
        const float xe0 = c2[0] + c2[1], xo0 = c2[0] - c2[1];
        const float xe1 = c2[2] + c2[3], xo1 = c2[2] - c2[3];
        const float xe2 = c2[4] + c2[5], xo2 = c2[4] - c2[5];
        const float xe3 = c2[6] + c2[7], xo3 = c2[6] - c2[7];
        const float ye0 = j2 ? (xe0 - xe1) : (xe0 + xe1);
        const float ye1 = j2 ? (xe2 - xe3) : (xe2 + xe3);
        const float yo0 = j2 ? (xo0 - xo1) : (xo0 + xo1);
        const float yo1 = j2 ? (xo2 - xo3) : (xo2 + xo3);
        a2[0] = SC * (i2 ? (ye0 - ye1) : (ye0 + ye1));
        a2[1] = SC * (i2 ? (yo0 - yo1) : (yo0 + yo1));
    }

    // ---- level 1: butterfly for this (i,j), both u and both k ----
    constexpr size_t p1 = 32 * 32 * 32;
    const float* s1 =
        scale1 + (size_t)b * 8 * p1 + ((size_t)d1 * 32 + h1) * 32 + 2 * tw;
    float a1v[4];  // [2u+k] = approx1 at (2d1+i, 2h1+j, 4tw+2u+k)
    {
        fvec2 c1[8];
        c1[0][0] = a2[0];
        c1[0][1] = a2[1];
#pragma unroll
        for (int s = 1; s < 8; ++s)
            c1[s] = *reinterpret_cast<const fvec2*>(s1 + s * p1);
#pragma unroll
        for (int u = 0; u < 2; ++u) {
            const float e0 = c1[0][u] + c1[1][u], q0 = c1[0][u] - c1[1][u];
            const float e1 = c1[2][u] + c1[3][u], q1 = c1[2][u] - c1[3][u];
            const float e2 = c1[4][u] + c1[5][u], q2 = c1[4][u] - c1[5][u];
            const float e3 = c1[6][u] + c1[7][u], q3 = c1[6][u] - c1[7][u];
            const float te = j ? (e0 - e1) : (e0 + e1);
            const float ue = j ? (e2 - e3) : (e2 + e3);
            const float to = j ? (q0 - q1) : (q0 + q1);
            const float uo = j ? (q2 - q3) : (q2 + q3);
            a1v[2 * u + 0] = SC * (i ? (te - ue) : (te + ue));
            a1v[2 * u + 1] = SC * (i ? (to - uo) : (to + uo));
        }
    }

    // ---- level 0: 4 butterflies (wc = 0..3) -> 2x2x8 output tile ----
    constexpr size_t p0 = 64 * 64 * 64;
    const int d0 = 2 * d1 + i, h0 = 2 * h1 + j;
    const float* src =
        scale0 + (size_t)b * 8 * p0 + ((size_t)d0 * 64 + h0) * 64 + 4 * tw;

    fvec4 det[8];  // s=1..7, [wc] = coarse-w offset within [4tw, 4tw+4)
#pragma unroll
    for (int s = 1; s < 8; ++s)
        det[s] = __builtin_nontemporal_load(reinterpret_cast<const fvec4*>(src + s * p0));

    float o[4][2][2][2];  // [wc][io][jo][ko]
#pragma unroll
    for (int wc = 0; wc < 4; ++wc) {
        const float ca = a1v[wc];
        const float g0 = det[1][wc];
        const float g1 = det[2][wc];
        const float g2 = det[3][wc];
        const float g3 = det[4][wc];
        const float g4 = det[5][wc];
        const float g5 = det[6][wc];
        const float g6 = det[7][wc];
        const float fe0 = ca + g0, fq0 = ca - g0;
        const float fe1 = g1 + g2, fq1 = g1 - g2;
        const float fe2 = g3 + g4, fq2 = g3 - g4;
        const float fe3 = g5 + g6, fq3 = g5 - g6;
        const float fee0 = fe0 + fe1, feo0 = fe0 - fe1;
        const float fee1 = fe2 + fe3, feo1 = fe2 - fe3;
        const float foe0 = fq0 + fq1, foo0 = fq0 - fq1;
        const float foe1 = fq2 + fq3, foo1 = fq2 - fq3;
        o[wc][0][0][0] = SC * (fee0 + fee1);
        o[wc][1][0][0] = SC * (fee0 - fee1);
        o[wc][0][1][0] = SC * (feo0 + feo1);
        o[wc][1][1][0] = SC * (feo0 - feo1);
        o[wc][0][0][1] = SC * (foe0 + foe1);
        o[wc][1][0][1] = SC * (foe0 - foe1);
        o[wc][0][1][1] = SC * (foo0 + foo1);
        o[wc][1][1][1] = SC * (foo0 - foo1);
    }

    // rows (2*d0+io, 2*h0+jo), w = [8*tw, 8*tw+8)
    float* ob = out + (size_t)b * 128 * 128 * 128 + (size_t)8 * tw;
#pragma unroll
    for (int io = 0; io < 2; ++io) {
#pragma unroll
        for (int jo = 0; jo < 2; ++jo) {
            float* p = ob + ((size_t)(2 * d0 + io) * 128 + (size_t)(2 * h0 + jo)) * 128;
            fvec4 lo, hi;
            lo[0] = o[0][io][jo][0];  // w offset 0  (wc=0, ko=0)
            lo[1] = o[0][io][jo][1];  // 1
            lo[2] = o[1][io][jo][0];  // 2
            lo[3] = o[1][io][jo][1];  // 3
            hi[0] = o[2][io][jo][0];  // 4
            hi[1] = o[2][io][jo][1];  // 5
            hi[2] = o[3][io][jo][0];  // 6
            hi[3] = o[3][io][jo][1];  // 7
            __builtin_nontemporal_store(lo, reinterpret_cast<fvec4*>(p));
            __builtin_nontemporal_store(hi, reinterpret_cast<fvec4*>(p + 4));
        }
    }
}

extern "C" void kernel_launch(void* const* d_in, const int* in_sizes, int n_in,
                              void* d_out, int out_size, void* d_ws, size_t ws_size,
                              hipStream_t stream) {
    const float* scale0 = (const float*)d_in[0];  // (B,8,64,64,64)
    const float* scale1 = (const float*)d_in[1];  // (B,8,32,32,32)
    const float* scale2 = (const float*)d_in[2];  // (B,8,16,16,16)
    float* out = (float*)d_out;                   // (B,1,128,128,128)

    const int B = in_sizes[0] / (8 * 64 * 64 * 64);  // 16
    const int total = B * 32 * 32 * 16 * 4;          // (w-pair voxel) x (i,j)
    idwt3_fused_kernel<<<(total + 255) / 256, 256, 0, stream>>>(scale0, scale1,
                                                                scale2, out, B);
}

// Round 7
// 46.891 us; speedup vs baseline: 1.3642x; 1.3642x over previous
//
#include <hip/hip_runtime.h>

typedef float fvec2 __attribute__((ext_vector_type(2)));
typedef float fvec4 __attribute__((ext_vector_type(4)));

// Fully fused 3-level inverse 3D Haar DWT, low-VGPR variant (R5 revert).
// out(B,128,128,128) from scale0(B,8,64^3), scale1(B,8,32^3), scale2(B,8,16^3).
// Subband s = 4*b0 + 2*b1 + b2 (b0 -> D, b1 -> H, b2 -> W); inverse level:
// out(2d+io,2h+jo,2w+ko) = 2^{-3/2} * sum_s c_s * (-1)^(io*b0+jo*b1+ko*b2).
//
// One thread per (level-1 voxel, i, j): recomputes the (cheap) level-2 and
// level-1 butterflies for its own (i,j) using runtime-sign selects, then does
// the two level-0 butterflies (k=0,1) and writes a 2x2x4 output tile.
// ~45 VGPR -> 8 waves/SIMD. Occupancy beats load width for this kernel
// (R4: 16B loads @ ~4 waves = 62.6us; R6: w-pair split = 64.0us; this: 47.1us).

__global__ __launch_bounds__(256, 8) void idwt3_fused_kernel(
    const float* __restrict__ scale0, const float* __restrict__ scale1,
    const float* __restrict__ scale2, float* __restrict__ out, int B) {
    constexpr float SC = 0.35355339059327373f;  // 2^{-3/2}

    const int idx = blockIdx.x * 256 + threadIdx.x;
    const int w1 = idx & 31;
    const int j = (idx >> 5) & 1;
    const int i = (idx >> 6) & 1;
    const int h1 = (idx >> 7) & 31;
    const int d1 = (idx >> 12) & 31;
    const int b = idx >> 17;
    if (b >= B) return;

    // ---- level 2: one approx2 value at (d1,h1,w1) ----
    const int d2 = d1 >> 1, h2 = h1 >> 1, w2 = w1 >> 1;
    const int i2 = d1 & 1, j2 = h1 & 1, k2 = w1 & 1;
    constexpr size_t p2 = 16 * 16 * 16;
    const float* s2 = scale2 + (size_t)b * 8 * p2 + ((size_t)d2 * 16 + h2) * 16 + w2;
    float a2;
    {
        float c2[8];
#pragma unroll
        for (int s = 0; s < 8; ++s) c2[s] = s2[s * p2];
        const float x0 = k2 ? (c2[0] - c2[1]) : (c2[0] + c2[1]);
        const float x1 = k2 ? (c2[2] - c2[3]) : (c2[2] + c2[3]);
        const float x2 = k2 ? (c2[4] - c2[5]) : (c2[4] + c2[5]);
        const float x3 = k2 ? (c2[6] - c2[7]) : (c2[6] + c2[7]);
        const float y0 = j2 ? (x0 - x1) : (x0 + x1);
        const float y1 = j2 ? (x2 - x3) : (x2 + x3);
        a2 = SC * (i2 ? (y0 - y1) : (y0 + y1));
    }

    // ---- level 1: butterfly restricted to this thread's (i,j), both k ----
    constexpr size_t p1 = 32 * 32 * 32;
    const float* s1 = scale1 + (size_t)b * 8 * p1 + ((size_t)d1 * 32 + h1) * 32 + w1;
    float a1k0, a1k1;  // a1[i][j][k] for k=0,1
    {
        float c1[8];
        c1[0] = a2;
#pragma unroll
        for (int s = 1; s < 8; ++s) c1[s] = s1[s * p1];
        const float e0 = c1[0] + c1[1], q0 = c1[0] - c1[1];
        const float e1 = c1[2] + c1[3], q1 = c1[2] - c1[3];
        const float e2 = c1[4] + c1[5], q2 = c1[4] - c1[5];
        const float e3 = c1[6] + c1[7], q3 = c1[6] - c1[7];
        const float te = j ? (e0 - e1) : (e0 + e1);
        const float ue = j ? (e2 - e3) : (e2 + e3);
        const float to = j ? (q0 - q1) : (q0 + q1);
        const float uo = j ? (q2 - q3) : (q2 + q3);
        a1k0 = SC * (i ? (te - ue) : (te + ue));
        a1k1 = SC * (i ? (to - uo) : (to + uo));
    }

    // ---- level 0: two butterflies (k=0,1) -> 2x2x4 output tile ----
    constexpr size_t p0 = 64 * 64 * 64;
    const int d0 = 2 * d1 + i, h0 = 2 * h1 + j;
    const float* src = scale0 + (size_t)b * 8 * p0 + ((size_t)d0 * 64 + h0) * 64 + 2 * w1;

    fvec2 det[8];  // s=1..7, [k] = w-offset within the pair
#pragma unroll
    for (int s = 1; s < 8; ++s)
        det[s] = __builtin_nontemporal_load(reinterpret_cast<const fvec2*>(src + s * p0));

    float o[2][2][2][2];  // [k][io][jo][ko]
#pragma unroll
    for (int k = 0; k < 2; ++k) {
        const float ca = (k == 0) ? a1k0 : a1k1;
        const float g0 = det[1][k];
        const float g1 = det[2][k];
        const float g2 = det[3][k];
        const float g3 = det[4][k];
        const float g4 = det[5][k];
        const float g5 = det[6][k];
        const float g6 = det[7][k];
        const float fe0 = ca + g0, fq0 = ca - g0;
        const float fe1 = g1 + g2, fq1 = g1 - g2;
        const float fe2 = g3 + g4, fq2 = g3 - g4;
        const float fe3 = g5 + g6, fq3 = g5 - g6;
        const float fee0 = fe0 + fe1, feo0 = fe0 - fe1;
        const float fee1 = fe2 + fe3, feo1 = fe2 - fe3;
        const float foe0 = fq0 + fq1, foo0 = fq0 - fq1;
        const float foe1 = fq2 + fq3, foo1 = fq2 - fq3;
        o[k][0][0][0] = SC * (fee0 + fee1);
        o[k][1][0][0] = SC * (fee0 - fee1);
        o[k][0][1][0] = SC * (feo0 + feo1);
        o[k][1][1][0] = SC * (feo0 - feo1);
        o[k][0][0][1] = SC * (foe0 + foe1);
        o[k][1][0][1] = SC * (foe0 - foe1);
        o[k][0][1][1] = SC * (foo0 + foo1);
        o[k][1][1][1] = SC * (foo0 - foo1);
    }

    // rows (2*d0+io, 2*h0+jo), w = [4*w1, 4*w1+4)
    float* ob = out + (size_t)b * 128 * 128 * 128 + (size_t)4 * w1;
#pragma unroll
    for (int io = 0; io < 2; ++io) {
#pragma unroll
        for (int jo = 0; jo < 2; ++jo) {
            fvec4 v;
            v[0] = o[0][io][jo][0];  // w = 4w1 + 0  (k=0, ko=0)
            v[1] = o[0][io][jo][1];  // w = 4w1 + 1  (k=0, ko=1)
            v[2] = o[1][io][jo][0];  // w = 4w1 + 2  (k=1, ko=0)
            v[3] = o[1][io][jo][1];  // w = 4w1 + 3  (k=1, ko=1)
            float* p = ob + ((size_t)(2 * d0 + io) * 128 + (size_t)(2 * h0 + jo)) * 128;
            __builtin_nontemporal_store(v, reinterpret_cast<fvec4*>(p));
        }
    }
}

extern "C" void kernel_launch(void* const* d_in, const int* in_sizes, int n_in,
                              void* d_out, int out_size, void* d_ws, size_t ws_size,
                              hipStream_t stream) {
    const float* scale0 = (const float*)d_in[0];  // (B,8,64,64,64)
    const float* scale1 = (const float*)d_in[1];  // (B,8,32,32,32)
    const float* scale2 = (const float*)d_in[2];  // (B,8,16,16,16)
    float* out = (float*)d_out;                   // (B,1,128,128,128)

    const int B = in_sizes[0] / (8 * 64 * 64 * 64);  // 16
    const int total = B * 32 * 32 * 32 * 4;          // (level-1 voxel) x (i,j)
    idwt3_fused_kernel<<<(total + 255) / 256, 256, 0, stream>>>(scale0, scale1,
                                                                scale2, out, B);
}